// Round 8
// baseline (4508.290 us; speedup 1.0000x reference)
//
#include <hip/hip_runtime.h>
#include <cstdint>
#include <cstddef>

// B=256, T=512, D=64, H=256, G=1024. Two-layer LSTM + FC.
// R8: gate-split pair scheme. Per batch-group, TWO blocks: half0 owns i,f gate
// rows (0-511), half1 owns g,o (512-1023). W per block = 256 KB -> FULLY
// CU-resident (128 KB LDS kf0-3 + 64 VGPR/wave kf4-7): zero per-step W stream
// (R7's 384 KB/step through the ~64 B/cyc CU port was the 6000-cyc bottleneck).
// Per step: each half writes its 2 gates' preacts(+xp, f32) to an L2 exchange
// buffer (parity double-buffered), release-flags the partner, acquire-spins on
// the partner's flag, reads all 4 gates, computes the cell REDUNDANTLY (both
// halves -> no h exchange; numerics bit-identical to R7).
// Pairing b <-> b+32 keeps pairs same-XCD under round-robin (heuristic only).
#define GATES 1024
#define SEQT  512
#define TCH   32
#define NCH   16
#define XPH   4194304    // elements per half per chunk: 32*16*8*64*16
#define XPT   131072     // elements per timestep per half: 16*8*64*16

using u16 = unsigned short;
using bf16x8 = __attribute__((ext_vector_type(8))) short;   // 8 bf16 = 4 VGPRs
using f32x4  = __attribute__((ext_vector_type(4))) float;

__device__ __forceinline__ float bf2f(u16 u) {
    union { float f; unsigned int i; } v; v.i = ((unsigned int)u) << 16; return v.f;
}
__device__ __forceinline__ u16 f2bf(float f) {
    union { float f; unsigned int i; } v; v.f = f;
    unsigned int r = v.i + 0x7FFFu + ((v.i >> 16) & 1u);   // RNE
    return (u16)(r >> 16);
}
// overflow-safe fast activations (v_exp + v_rcp, ~1 ulp)
__device__ __forceinline__ float sigm(float x) {
    return __builtin_amdgcn_rcpf(1.f + __expf(-x));
}
__device__ __forceinline__ float tanh_f(float x) {
    return 1.f - 2.f * __builtin_amdgcn_rcpf(1.f + __expf(2.f * x));
}

// ---------------- prep ----------------
__global__ void k_conv(const float* __restrict__ src, u16* __restrict__ dst, int n) {
    int i = blockIdx.x * 256 + threadIdx.x;
    if (i < n) dst[i] = f2bf(src[i]);
}
__global__ void k_bias(const float* __restrict__ a, const float* __restrict__ b,
                       float* __restrict__ o, int n) {
    int i = blockIdx.x * 256 + threadIdx.x;
    if (i < n) o[i] = a[i] + b[i];
}
__global__ void k_zero(unsigned int* __restrict__ p, int n) {
    int i = blockIdx.x * 64 + threadIdx.x;
    if (i < n) p[i] = 0u;
}

// ---------------- fused input-projection GEMM ----------------
// blocks 0-511: layer0 (A=xb [256][512][64], K=64); 512-1023: layer1 (A=h0c).
// Epilogue scatters to the R8 rec-order:
//   el = half*XPH + (((tloc*16+blk)*8 + w)*64 + qr*16 + mlr)*16 + fi*4 + r_r
__global__ __launch_bounds__(256, 2) void gemm_fused(
    const u16* __restrict__ A0, const u16* __restrict__ W0,
    const float* __restrict__ b0, u16* __restrict__ o0, int t00,
    const u16* __restrict__ A1, const u16* __restrict__ W1,
    const float* __restrict__ b1, u16* __restrict__ o1, int it)
{
    const int half_ = blockIdx.x >> 9;
    if (half_ == 0 && it >= NCH) return;
    if (half_ == 1 && it == 0) return;
    const int bid = blockIdx.x & 511;

    const u16* A; const u16* W; const float* bias; u16* out;
    int K, As_b, As_t, t0;
    if (half_ == 0) { A = A0; W = W0; bias = b0; out = o0; K = 64;  As_b = 32768; As_t = 64;    t0 = t00; }
    else            { A = A1; W = W1; bias = b1; out = o1; K = 256; As_b = 256;   As_t = 65536; t0 = 0;   }

    __shared__ __align__(16) u16 As[128][40];
    __shared__ __align__(16) u16 Bs[128][40];
    const int tid  = threadIdx.x;
    const int mb   = bid >> 3, nb = bid & 7;
    const int n0   = nb * 128;
    const int wave = tid >> 6, lane = tid & 63;
    const int wm   = wave >> 1, wn = wave & 1;
    const int ml   = lane & 15, q = lane >> 4;
    const int tloc = mb >> 1;
    const int tt   = t0 + tloc;
    const int bbas = (mb & 1) * 128;

    f32x4 acc[4][4];
    #pragma unroll
    for (int mi = 0; mi < 4; ++mi)
        #pragma unroll
        for (int ni = 0; ni < 4; ++ni)
            acc[mi][ni] = (f32x4)0.f;

    const int nk = K >> 5;
    for (int kt = 0; kt < nk; ++kt) {
        __syncthreads();
        #pragma unroll
        for (int i = 0; i < 2; ++i) {
            int c = tid + i * 256;
            int row = c >> 2, kb = c & 3;
            *(uint4*)&As[row][kb * 8] = *(const uint4*)(
                A + (size_t)(bbas + row) * As_b + (size_t)tt * As_t + kt * 32 + kb * 8);
            *(uint4*)&Bs[row][kb * 8] = *(const uint4*)(
                W + (size_t)(n0 + row) * K + kt * 32 + kb * 8);
        }
        __syncthreads();
        bf16x8 af[4], bfr[4];
        #pragma unroll
        for (int mi = 0; mi < 4; ++mi)
            af[mi] = *(const bf16x8*)&As[wm * 64 + mi * 16 + ml][q * 8];
        #pragma unroll
        for (int ni = 0; ni < 4; ++ni)
            bfr[ni] = *(const bf16x8*)&Bs[wn * 64 + ni * 16 + ml][q * 8];
        #pragma unroll
        for (int mi = 0; mi < 4; ++mi)
            #pragma unroll
            for (int ni = 0; ni < 4; ++ni)
                acc[mi][ni] = __builtin_amdgcn_mfma_f32_16x16x32_bf16(
                    af[mi], bfr[ni], acc[mi][ni], 0, 0, 0);
    }

    #pragma unroll
    for (int ni = 0; ni < 4; ++ni) {
        int gc = n0 + wn * 64 + ni * 16 + ml;
        int gh = gc >> 9;              // which half's buffer
        int w  = (gc >> 6) & 7;
        int fi = (gc >> 4) & 3;
        int mlr = gc & 15;
        float bv = bias[gc];
        #pragma unroll
        for (int mi = 0; mi < 4; ++mi) {
            int b0r = bbas + wm * 64 + mi * 16 + q * 4;
            #pragma unroll
            for (int rr = 0; rr < 4; ++rr) {
                int bb = b0r + rr;
                int blk = bb >> 4, qr = (bb >> 2) & 3, r_r = bb & 3;
                size_t el = (size_t)gh * XPH
                    + ((size_t)(((tloc * 16 + blk) * 8 + w) * 64 + qr * 16 + mlr)) * 16
                    + fi * 4 + r_r;
                out[el] = f2bf(acc[mi][ni][rr] + bv);
            }
        }
    }
}

// ---------------- paired LSTM recurrence ----------------
// 64 blocks x 512 thr. b: H = b>>5 (gate half), L = (b>>4)&1 (layer), grp=b&15.
// Wave owns 64 gate rows (base H*512 + wave*64), 4 B-frags x 8 kf:
// kf0-3 from LDS WL (staged once), kf4-7 from wreg[4][4] (64 VGPR). acc[4] in
// AGPRs. hA double-buffered. Exchange: ex[L*16+grp] = [par][gt][m][j] f32.
__global__ __launch_bounds__(512, 2) void lstm_rec2(
    const u16* __restrict__ xp0, const u16* __restrict__ xp1,
    const u16* __restrict__ W0,  const u16* __restrict__ W1,
    u16* __restrict__ h0c, float* __restrict__ hlast,
    u16* __restrict__ hs0, float* __restrict__ cs0,
    u16* __restrict__ hs1, float* __restrict__ cs1,
    float* __restrict__ exbuf, unsigned int* __restrict__ flags, int it)
{
    const int b   = blockIdx.x;
    const int H   = b >> 5;
    const int L   = (b >> 4) & 1;
    const int grp = b & 15;
    if (L == 0 && it >= NCH) return;
    if (L == 1 && it == 0) return;
    const int chunk = L ? it - 1 : it;
    const u16* xp = (L ? xp1 : xp0) + (size_t)H * XPH;
    const u16* W  = L ? W1 : W0;
    u16*  hs = L ? hs1 : hs0;
    float* cs = L ? cs1 : cs0;
    const int init = (chunk == 0);

    float* ex = exbuf + (size_t)(L * 16 + grp) * 32768;   // 2par*4gt*16*256 f32
    unsigned int* flp = flags + (L * 16 + grp) * 2 + H;
    unsigned int* flq = flags + (L * 16 + grp) * 2 + (1 - H);

    __shared__ __align__(16) u16 WL[65536];          // 131072 B: kf0-3 frag-order
    __shared__ __align__(16) u16 hA[2][16][264];     // 16896 B double buffer

    const int tid  = threadIdx.x;
    const int wave = tid >> 6, lane = tid & 63;
    const int ml   = lane & 15, q = lane >> 4;
    const int ub   = wave * 32;
    const int bb0  = grp * 16;

    // this wave's 4 B-frag row groups: g = H*512 + wave*64 + fi*16 + ml
    int woff_[4];
    #pragma unroll
    for (int fi = 0; fi < 4; ++fi)
        woff_[fi] = (H * 512 + wave * 64 + fi * 16 + ml) * 256 + q * 8;

    // stage kf0-3 into LDS (per-wave region, contiguous 16 B per lane per slot)
    const int wlb = wave * 8192 + lane * 8;
    #pragma unroll
    for (int kf = 0; kf < 4; ++kf)
        #pragma unroll
        for (int fi = 0; fi < 4; ++fi)
            *(bf16x8*)&WL[wlb + (kf * 4 + fi) * 512] =
                *(const bf16x8*)(W + woff_[fi] + kf * 32);

    // kf4-7 persistent in registers (64 VGPR)
    bf16x8 wreg[4][4];
    #pragma unroll
    for (int kf = 4; kf < 8; ++kf)
        #pragma unroll
        for (int fi = 0; fi < 4; ++fi)
            wreg[kf - 4][fi] = *(const bf16x8*)(W + woff_[fi] + kf * 32);

    float c_[8];
    if (init) {
        for (int i = tid; i < 16 * 264; i += 512) ((u16*)&hA[0][0][0])[i] = 0;
        #pragma unroll
        for (int i = 0; i < 8; ++i) c_[i] = 0.f;
    } else {
        int m = tid >> 5, j0 = (tid & 31) * 8;
        *(bf16x8*)&hA[0][m][j0] = *(const bf16x8*)&hs[(size_t)(bb0 + m) * 256 + j0];
        #pragma unroll
        for (int s = 0; s < 2; ++s)
            #pragma unroll
            for (int r = 0; r < 4; ++r)
                c_[s * 4 + r] = cs[(size_t)(bb0 + q * 4 + r) * 256 + ub + s * 16 + ml];
    }

    const u16* xpl = xp + ((size_t)(grp * 8 + wave) * 64 + lane) * 16;

    __syncthreads();

    for (int t = 0; t < TCH; ++t) {
        const int br = t & 1, bw = br ^ 1;
        const int gstep = chunk * TCH + t;
        const int par = gstep & 1;

        // this lane's xp slice: 16 bf16 = 32 B ((fi,r)-packed)
        bf16x8 xv0 = *(const bf16x8*)(xpl);
        bf16x8 xv1 = *(const bf16x8*)(xpl + 8);

        f32x4 acc[4];
        #pragma unroll
        for (int fi = 0; fi < 4; ++fi) acc[fi] = (f32x4)0.f;

        #pragma unroll
        for (int kf = 0; kf < 4; ++kf) {
            bf16x8 a = *(const bf16x8*)&hA[br][ml][kf * 32 + q * 8];
            #pragma unroll
            for (int fi = 0; fi < 4; ++fi)
                acc[fi] = __builtin_amdgcn_mfma_f32_16x16x32_bf16(
                    a, *(const bf16x8*)&WL[wlb + (kf * 4 + fi) * 512], acc[fi], 0, 0, 0);
        }
        #pragma unroll
        for (int kf = 4; kf < 8; ++kf) {
            bf16x8 a = *(const bf16x8*)&hA[br][ml][kf * 32 + q * 8];
            #pragma unroll
            for (int fi = 0; fi < 4; ++fi)
                acc[fi] = __builtin_amdgcn_mfma_f32_16x16x32_bf16(
                    a, wreg[kf - 4][fi], acc[fi], 0, 0, 0);
        }

        // publish this half's 2 gates: preact = acc + xp (f32)
        {
            const int gt = H * 2 + (wave >> 2);
            float* exw = ex + (size_t)(par * 4 + gt) * 4096;
            #pragma unroll
            for (int fi = 0; fi < 4; ++fi) {
                int j = (wave & 3) * 64 + fi * 16 + ml;
                bf16x8 xv = (fi < 2) ? xv0 : xv1;
                #pragma unroll
                for (int r = 0; r < 4; ++r)
                    exw[(q * 4 + r) * 256 + j] =
                        acc[fi][r] + bf2f((u16)xv[(fi & 1) * 4 + r]);
            }
        }
        __syncthreads();   // all preact stores drained (vmcnt) block-wide
        if (tid == 0) {
            __threadfence();
            __hip_atomic_store(flp, (unsigned)(gstep + 1),
                               __ATOMIC_RELEASE, __HIP_MEMORY_SCOPE_AGENT);
            while (__hip_atomic_load(flq, __ATOMIC_RELAXED,
                                     __HIP_MEMORY_SCOPE_AGENT) < (unsigned)(gstep + 1)) { }
            (void)__hip_atomic_load(flq, __ATOMIC_ACQUIRE, __HIP_MEMORY_SCOPE_AGENT);
        }
        __syncthreads();

        // cell phase (redundant on both halves): read all 4 gates
        const float* exr = ex + (size_t)(par * 4) * 4096;
        #pragma unroll
        for (int s = 0; s < 2; ++s) {
            int j = ub + s * 16 + ml;
            #pragma unroll
            for (int r = 0; r < 4; ++r) {
                int m = q * 4 + r;
                float pi = exr[(0 * 16 + m) * 256 + j];
                float pf = exr[(1 * 16 + m) * 256 + j];
                float pg = exr[(2 * 16 + m) * 256 + j];
                float po = exr[(3 * 16 + m) * 256 + j];
                float ig = sigm(pi), fg = sigm(pf);
                float gg = tanh_f(pg), og = sigm(po);
                float cc = fg * c_[s * 4 + r] + ig * gg;
                c_[s * 4 + r] = cc;
                float h = og * tanh_f(cc);
                u16 hb = f2bf(h);
                hA[bw][m][j] = hb;
                if (H == 0) {
                    if (L == 0)
                        h0c[((size_t)t * 256 + bb0 + m) * 256 + j] = hb;
                    else if (chunk == NCH - 1 && t == TCH - 1)
                        hlast[(size_t)(bb0 + m) * 256 + j] = h;
                }
            }
        }
        xpl += XPT;
        __syncthreads();   // h(t+1) published in buf bw
    }

    // persist state (half0 only; both halves hold identical values)
    if (H == 0) {
        #pragma unroll
        for (int s = 0; s < 2; ++s)
            #pragma unroll
            for (int r = 0; r < 4; ++r)
                cs[(size_t)(bb0 + q * 4 + r) * 256 + ub + s * 16 + ml] = c_[s * 4 + r];
        int m = tid >> 5, j0 = (tid & 31) * 8;
        *(bf16x8*)&hs[(size_t)(bb0 + m) * 256 + j0] = *(const bf16x8*)&hA[0][m][j0];
    }
}

// ---------------- FC head ----------------
__global__ void fc_k(const float* __restrict__ h, const float* __restrict__ w,
                     const float* __restrict__ b, float* __restrict__ out)
{
    int bb = blockIdx.x, lane = threadIdx.x;
    float s = 0.f;
    for (int j = lane; j < 256; j += 64) s += h[bb * 256 + j] * w[j];
    #pragma unroll
    for (int off = 32; off > 0; off >>= 1) s += __shfl_down(s, off);
    if (lane == 0) out[bb] = s + b[0];
}

extern "C" void kernel_launch(void* const* d_in, const int* in_sizes, int n_in,
                              void* d_out, int out_size, void* d_ws, size_t ws_size,
                              hipStream_t stream)
{
    const float* x    = (const float*)d_in[0];
    const float* Wih0 = (const float*)d_in[1];
    const float* Whh0 = (const float*)d_in[2];
    const float* bih0 = (const float*)d_in[3];
    const float* bhh0 = (const float*)d_in[4];
    const float* Wih1 = (const float*)d_in[5];
    const float* Whh1 = (const float*)d_in[6];
    const float* bih1 = (const float*)d_in[7];
    const float* bhh1 = (const float*)d_in[8];
    const float* fcw  = (const float*)d_in[9];
    const float* fcb  = (const float*)d_in[10];
    float* out = (float*)d_out;

    // workspace layout, total ~61.5 MB
    char* ws = (char*)d_ws;
    u16*   xp0   = (u16*)(ws);                  // 16777216
    u16*   xp1   = (u16*)(ws + 16777216);       // 16777216
    u16*   h0c   = (u16*)(ws + 33554432);       //  4194304  [32][256][256] bf16
    u16*   xb    = (u16*)(ws + 37748736);       // 16777216  [256][512][64] bf16
    u16*   Wih0b = (u16*)(ws + 54525952);       //   131072
    u16*   Whh0b = (u16*)(ws + 54657024);       //   524288
    u16*   Wih1b = (u16*)(ws + 55181312);       //   524288
    u16*   Whh1b = (u16*)(ws + 55705600);       //   524288
    float* bias0 = (float*)(ws + 56229888);     //     4096
    float* bias1 = (float*)(ws + 56233984);     //     4096
    u16*   hs0   = (u16*)(ws + 56238080);       //   131072
    float* cs0   = (float*)(ws + 56369152);     //   262144
    u16*   hs1   = (u16*)(ws + 56631296);       //   131072
    float* cs1   = (float*)(ws + 56762368);     //   262144
    float* h1l   = (float*)(ws + 57024512);     //   262144
    float* exbuf = (float*)(ws + 57286656);     //  4194304  [32][2][4][16][256] f32
    unsigned int* flags = (unsigned int*)(ws + 61480960);   // 256

    k_zero<<<1, 64, 0, stream>>>(flags, 64);
    k_conv<<<32768, 256, 0, stream>>>(x, xb, 8388608);
    k_conv<<<256,   256, 0, stream>>>(Wih0, Wih0b, 65536);
    k_conv<<<1024,  256, 0, stream>>>(Whh0, Whh0b, 262144);
    k_conv<<<1024,  256, 0, stream>>>(Wih1, Wih1b, 262144);
    k_conv<<<1024,  256, 0, stream>>>(Whh1, Whh1b, 262144);
    k_bias<<<4, 256, 0, stream>>>(bih0, bhh0, bias0, 1024);
    k_bias<<<4, 256, 0, stream>>>(bih1, bhh1, bias1, 1024);

    for (int it = 0; it <= NCH; ++it) {
        gemm_fused<<<1024, 256, 0, stream>>>(xb, Wih0b, bias0, xp0, it * TCH,
                                             h0c, Wih1b, bias1, xp1, it);
        lstm_rec2<<<64, 512, 0, stream>>>(xp0, xp1, Whh0b, Whh1b, h0c, h1l,
                                          hs0, cs0, hs1, cs1, exbuf, flags, it);
    }
    fc_k<<<256, 64, 0, stream>>>(h1l, fcw, fcb, out);
}